// Round 13
// baseline (2229.922 us; speedup 1.0000x reference)
//
#include <hip/hip_runtime.h>

#define BATCH 262144
#define MARGIN 1e-5f
#define LIST_CAP (1u<<20)

typedef __attribute__((ext_vector_type(8))) short short8;
typedef __attribute__((ext_vector_type(16))) float f32x16;

// ---------------- workspace layout (bytes) ----------------
// 0       : Rt64 f64[128][128]  Rt64[j*128+k] = R[k][j]      (131072)
// 131072  : img  u16: i1h[16384] i1l[16384] i2h[16384] i2l[16384] (131072)
// 262144  : counter u32
// 262912  : list u32[LIST_CAP]                                (4 MB)
// 4457216 : M64 f64[128][128]   I+A (exact)                   (131072)

__device__ __forceinline__ unsigned f2bf(float f) {
  unsigned u = __float_as_uint(f);
  return (u + 0x7FFFu + ((u >> 16) & 1u)) >> 16;   // RTN-even bf16
}

// =======================================================================
// K_inv: ONE kernel replaces GJ + kref chain. Single block, 1024 thr.
// Math: S = (I+A)(I-A) = I - A^2 is SPD, eig in [1, 1+sig^2]; Newton-
// Schulz Z' = Z(2I - S Z) from Z0 = cI, c = 2/(2+||A||_F^2) converges
// unconditionally (r = F2/(2+F2)). Then Ytil = Z(I-A) ~ (I+A)^-1; three
// f64 Newton steps on M = I+A polish to f64 ulp. All matrices in LDS;
// per-thread state is scalar partials (spill-proof; no serial GJ loop).
// Emits Rt64 (R = 2*(I+A)^-1 - I) + bf16-split fragment images.
// LDS: S32[128][129]@0 (66048) | Y32[128][129]@66048 | T32[128][17]@132096
//      f64 phase: Y64[128][129]@0 (132096) | T64[128][17]@132096 | scal@149504
// =======================================================================
__global__ __attribute__((amdgpu_waves_per_eu(4, 4))) __launch_bounds__(1024)
void kinv(const float* __restrict__ skew, double* __restrict__ M64,
          double* __restrict__ Rt64, unsigned short* __restrict__ img,
          unsigned int* __restrict__ counter)
{
  extern __shared__ char sm[];
  float*  S32  = (float*)sm;                  // A, then S = I - A^2
  float*  Y32  = (float*)(sm + 66048);
  float*  T32  = (float*)(sm + 132096);
  double* Y64  = (double*)sm;
  double* T64  = (double*)(sm + 132096);
  float*  scal = (float*)(sm + 149504);

  const int tid  = threadIdx.x;
  const int lane = tid & 63;
  const int m    = tid >> 3;        // row 0..127
  const int s    = tid & 7;
  const int lc   = s * 2;           // local col pair within a 16-col tile

  if (tid == 0) { *counter = 0u; scal[0] = 0.f; }

  // ---- build A (LDS) + M64 = I+A (global) + F^2 partial ----
  float fsq = 0.f;
  #pragma unroll
  for (int e = 0; e < 16; ++e) {
    int j = s + 8*e;
    float v = 0.f;
    if (m < j)      v =  skew[m*127 - (m*(m-1))/2 + (j - m - 1)];
    else if (m > j) v = -skew[j*127 - (j*(j-1))/2 + (m - j - 1)];
    S32[m*129 + j] = v;
    M64[m*128 + j] = (m == j) ? 1.0 : (double)v;
    fsq += v*v;
  }
  fsq += __shfl_xor(fsq, 1);  fsq += __shfl_xor(fsq, 2);
  fsq += __shfl_xor(fsq, 4);  fsq += __shfl_xor(fsq, 8);
  fsq += __shfl_xor(fsq, 16); fsq += __shfl_xor(fsq, 32);
  __syncthreads();                           // A complete, scal zeroed
  if (lane == 0) atomicAdd(&scal[0], fsq);
  __syncthreads();
  const float F2 = scal[0];
  const float c0 = 2.f / (2.f + F2);

  // ---- S = I - A*A (regs), then overwrite A; Y0 = c0*I ----
  {
    float sreg[16];
    #pragma unroll
    for (int cI = 0; cI < 16; ++cI) {
      const int col = s*16 + cI;
      float a0 = 0.f, a1 = 0.f;
      for (int j = 0; j < 128; j += 2) {
        a0 = fmaf(S32[m*129+j],   S32[j*129+col],     a0);
        a1 = fmaf(S32[m*129+j+1], S32[(j+1)*129+col], a1);
      }
      sreg[cI] = ((m == col) ? 1.f : 0.f) - (a0 + a1);
    }
    __syncthreads();                         // all A reads done
    #pragma unroll
    for (int cI = 0; cI < 16; ++cI) {
      const int col = s*16 + cI;
      S32[m*129+col] = sreg[cI];
      Y32[m*129+col] = (m == col) ? c0 : 0.f;
    }
  }
  __syncthreads();

  // ---- 10x f32 Newton: Y' = 2Y - Y*(S*Y) ----
  for (int it = 0; it < 10; ++it) {
    float yn[16];
    #pragma unroll
    for (int t8 = 0; t8 < 8; ++t8) {
      const int gc = t8*16 + lc;
      float a0=0,a1=0,b0=0,b1=0;
      for (int j = 0; j < 128; j += 2) {
        float s0 = S32[m*129+j], s1 = S32[m*129+j+1];
        a0 = fmaf(s0, Y32[j*129+gc],       a0);
        a1 = fmaf(s1, Y32[(j+1)*129+gc],   a1);
        b0 = fmaf(s0, Y32[j*129+gc+1],     b0);
        b1 = fmaf(s1, Y32[(j+1)*129+gc+1], b1);
      }
      T32[m*17+lc]   = a0 + a1;
      T32[m*17+lc+1] = b0 + b1;
      __syncthreads();                       // T tile ready
      a0=0; a1=0; b0=0; b1=0;
      for (int j = 0; j < 128; j += 2) {
        float y0 = Y32[m*129+j], y1 = Y32[m*129+j+1];
        a0 = fmaf(y0, T32[j*17+lc],       a0);
        a1 = fmaf(y1, T32[(j+1)*17+lc],   a1);
        b0 = fmaf(y0, T32[j*17+lc+1],     b0);
        b1 = fmaf(y1, T32[(j+1)*17+lc+1], b1);
      }
      yn[t8*2]   = 2.f*Y32[m*129+gc]   - (a0 + a1);
      yn[t8*2+1] = 2.f*Y32[m*129+gc+1] - (b0 + b1);
      __syncthreads();                       // T consumed
    }
    #pragma unroll
    for (int t8 = 0; t8 < 8; ++t8) {
      Y32[m*129 + t8*16 + lc]     = yn[t8*2];
      Y32[m*129 + t8*16 + lc + 1] = yn[t8*2+1];
    }
    __syncthreads();
  }

  // ---- Ytil = Z*(I-A), (I-A) = 2I - M64, into f64 regs ----
  double yn64[16];
  #pragma unroll
  for (int t8 = 0; t8 < 8; ++t8) {
    const int gc = t8*16 + lc;
    T32[m*17+lc]   = ((m == gc  ) ? 2.f : 0.f) - (float)M64[m*128+gc];
    T32[m*17+lc+1] = ((m == gc+1) ? 2.f : 0.f) - (float)M64[m*128+gc+1];
    __syncthreads();
    float a0=0,a1=0,b0=0,b1=0;
    for (int j = 0; j < 128; j += 2) {
      float y0 = Y32[m*129+j], y1 = Y32[m*129+j+1];
      a0 = fmaf(y0, T32[j*17+lc],       a0);
      a1 = fmaf(y1, T32[(j+1)*17+lc],   a1);
      b0 = fmaf(y0, T32[j*17+lc+1],     b0);
      b1 = fmaf(y1, T32[(j+1)*17+lc+1], b1);
    }
    yn64[t8*2]   = (double)(a0 + a1);
    yn64[t8*2+1] = (double)(b0 + b1);
    __syncthreads();
  }
  // Y32/S32 dead -> repurpose LDS as Y64
  #pragma unroll
  for (int t8 = 0; t8 < 8; ++t8) {
    Y64[m*129 + t8*16 + lc]     = yn64[t8*2];
    Y64[m*129 + t8*16 + lc + 1] = yn64[t8*2+1];
  }
  __syncthreads();

  // ---- 3x f64 Newton on M = I+A (rows from global, L1-hot) ----
  for (int it = 0; it < 3; ++it) {
    double dn[16];
    #pragma unroll
    for (int t8 = 0; t8 < 8; ++t8) {
      const int gc = t8*16 + lc;
      const double* Mrow = M64 + (size_t)m*128;
      double a0=0,a1=0,b0=0,b1=0;
      for (int j = 0; j < 128; j += 2) {
        double m0 = Mrow[j], m1 = Mrow[j+1];
        a0 = fma(m0, Y64[j*129+gc],       a0);
        a1 = fma(m1, Y64[(j+1)*129+gc],   a1);
        b0 = fma(m0, Y64[j*129+gc+1],     b0);
        b1 = fma(m1, Y64[(j+1)*129+gc+1], b1);
      }
      T64[m*17+lc]   = a0 + a1;
      T64[m*17+lc+1] = b0 + b1;
      __syncthreads();
      a0=0; a1=0; b0=0; b1=0;
      for (int j = 0; j < 128; j += 2) {
        double y0 = Y64[m*129+j], y1 = Y64[m*129+j+1];
        a0 = fma(y0, T64[j*17+lc],       a0);
        a1 = fma(y1, T64[(j+1)*17+lc],   a1);
        b0 = fma(y0, T64[j*17+lc+1],     b0);
        b1 = fma(y1, T64[(j+1)*17+lc+1], b1);
      }
      dn[t8*2]   = 2.0*Y64[m*129+gc]   - (a0 + a1);
      dn[t8*2+1] = 2.0*Y64[m*129+gc+1] - (b0 + b1);
      __syncthreads();
    }
    #pragma unroll
    for (int t8 = 0; t8 < 8; ++t8) {
      Y64[m*129 + t8*16 + lc]     = dn[t8*2];
      Y64[m*129 + t8*16 + lc + 1] = dn[t8*2+1];
    }
    __syncthreads();
  }

  // ---- emission: R = 2*(I+A)^-1 - I ----
  #pragma unroll
  for (int e = 0; e < 16; ++e) {
    const int j = s + 8*e;
    double v = 2.0*Y64[m*129 + j] - ((m == j) ? 1.0 : 0.0);   // R[m][j]
    Rt64[j*128 + m] = v;
    float r32 = (float)v;
    unsigned hh = f2bf(r32);
    unsigned ll = f2bf(r32 - __uint_as_float(hh << 16));
    int off1 = (((m>>5)*8 + (j>>4))*64 + ((((j>>3)&1)<<5) | (m&31)))*8 + (j&7);
    img[off1]          = (unsigned short)hh;
    img[16384 + off1]  = (unsigned short)ll;
    int off2 = (((j>>5)*8 + (m>>4))*64 + ((((m>>3)&1)<<5) | (j&31)))*8 + (m&7);
    img[32768 + off2]  = (unsigned short)hh;
    img[49152 + off2]  = (unsigned short)ll;
  }
}

// =======================================================================
// K_main: round-12 form, unchanged (best measured: 131 us, no spills).
// =======================================================================
#define MM3(ACC, XH, XL, BH, BL)                                        \
  ACC = __builtin_amdgcn_mfma_f32_32x32x16_bf16(XH, BH, ACC, 0, 0, 0);  \
  ACC = __builtin_amdgcn_mfma_f32_32x32x16_bf16(XL, BH, ACC, 0, 0, 0);  \
  ACC = __builtin_amdgcn_mfma_f32_32x32x16_bf16(XH, BL, ACC, 0, 0, 0);

#define LGKM_BAR()                                                      \
  asm volatile("s_waitcnt lgkmcnt(0)" ::: "memory");                    \
  __builtin_amdgcn_s_barrier();                                         \
  __builtin_amdgcn_sched_barrier(0);

__global__ __launch_bounds__(256, 2)
void kmain(const float* __restrict__ x, const float* __restrict__ mean,
           const float* __restrict__ cent, const unsigned short* __restrict__ img,
           float* __restrict__ out,
           unsigned int* __restrict__ counter, unsigned int* __restrict__ list)
{
  __shared__ __align__(16) unsigned short Xh[2][32*128];
  __shared__ __align__(16) unsigned short Xl[2][32*128];
  __shared__ __align__(16) unsigned short Qh[2][32*128];
  __shared__ __align__(16) unsigned short Ql[2][32*128];
  __shared__ float norms[4][32];     // per-wave private
  __shared__ float invs[4][32];

  const int tid = threadIdx.x, lane = tid & 63, w = tid >> 6;
  const int al = lane & 31, ah = lane >> 5;

  short8 B1h[8], B1l[8], B2h[8], B2l[8];
  #pragma unroll
  for (int t = 0; t < 8; ++t) {
    size_t o = (size_t)((w*8 + t)*64 + lane)*8;
    B1h[t] = *(const short8*)(img +         o);
    B1l[t] = *(const short8*)(img + 16384 + o);
    B2h[t] = *(const short8*)(img + 32768 + o);
    B2l[t] = *(const short8*)(img + 49152 + o);
  }

  const float c0 = cent[0], c1 = cent[1], c2 = cent[2], c3 = cent[3];
  const float c4 = cent[4], c5 = cent[5], c6 = cent[6], c7 = cent[7];
  const float mid0 = 0.5f*(c0+c1), mid1 = 0.5f*(c1+c2), mid2 = 0.5f*(c2+c3),
              mid3 = 0.5f*(c3+c4), mid4 = 0.5f*(c4+c5), mid5 = 0.5f*(c5+c6),
              mid6 = 0.5f*(c6+c7);
  unsigned qt0, qt1, qt2, qt3, qt4, qt5, qt6, qt7;
  {
    #define PS(C, QT) { unsigned h = f2bf(C); float hf = __uint_as_float(h<<16); \
                        QT = (h<<16) | f2bf((C) - hf); }
    PS(c0,qt0) PS(c1,qt1) PS(c2,qt2) PS(c3,qt3)
    PS(c4,qt4) PS(c5,qt5) PS(c6,qt6) PS(c7,qt7)
    #undef PS
  }

  const float2 mean2 = *(const float2*)(mean + 2*lane);
  const float meanv = mean[w*32 + al];

  const int row0 = blockIdx.x * 256;

  float2 xpf[8];
  #pragma unroll
  for (int rr = 0; rr < 8; ++rr)
    xpf[rr] = *(const float2*)(x + (size_t)(row0 + w*8 + rr)*128 + 2*lane);

  const bool own = (((al >> 2) & 1) == ah);
  const int rrq = al - 4*ah;
  const int gsel = (rrq & 3) + 4*(rrq >> 3);

  for (int ch = 0; ch < 8; ++ch) {
    const int chb = row0 + ch*32;
    const int p = ch & 1;

    // ---- Phase A: issue next-chunk loads; cvt_pk split -> X[p] ----
    float2 xn[8];
    if (ch < 7) {
      #pragma unroll
      for (int rr = 0; rr < 8; ++rr)
        xn[rr] = *(const float2*)(x + (size_t)(chb + 32 + w*8 + rr)*128 + 2*lane);
    }
    #pragma unroll
    for (int rr = 0; rr < 8; ++rr) {
      const int r = w*8 + rr;
      float a = xpf[rr].x - mean2.x;
      float b = xpf[rr].y - mean2.y;
      unsigned ph, pl;
      asm("v_cvt_pk_bf16_f32 %0, %1, %2" : "=v"(ph) : "v"(a), "v"(b));
      float ha = __uint_as_float(ph << 16);
      float hb = __uint_as_float(ph & 0xFFFF0000u);
      float ra = a - ha, rb = b - hb;
      asm("v_cvt_pk_bf16_f32 %0, %1, %2" : "=v"(pl) : "v"(ra), "v"(rb));
      unsigned off = ((unsigned)(r*256 + 4*lane)) ^ (((unsigned)(r & 7)) << 4);
      *(unsigned*)((char*)&Xh[p][0] + off) = ph;
      *(unsigned*)((char*)&Xl[p][0] + off) = pl;
    }
    #pragma unroll
    for (int rr = 0; rr < 8; ++rr) xpf[rr] = xn[rr];
    LGKM_BAR();                                       // bar1: X[p] ready

    // ---- Phase B: norm-MFMA + mm1, quantize, write Q[p] ----
    f32x16 accN, accA, accB;
    #pragma unroll
    for (int g = 0; g < 16; ++g) { accN[g] = 0.0f; accA[g] = 0.0f; accB[g] = 0.0f; }
    __builtin_amdgcn_s_setprio(1);
    #pragma unroll
    for (int t = 0; t < 8; ++t) {
      unsigned fb = ((unsigned)(al*256 + t*32 + ah*16)) ^ (((unsigned)(al & 7)) << 4);
      short8 xh = *(const short8*)((const char*)&Xh[p][0] + fb);
      short8 xl = *(const short8*)((const char*)&Xl[p][0] + fb);
      accN = __builtin_amdgcn_mfma_f32_32x32x16_bf16(xh, xh, accN, 0, 0, 0);
      accN = __builtin_amdgcn_mfma_f32_32x32x16_bf16(xl, xh, accN, 0, 0, 0);
      accN = __builtin_amdgcn_mfma_f32_32x32x16_bf16(xh, xl, accN, 0, 0, 0);
      if (t & 1) { MM3(accB, xh, xl, B1h[t], B1l[t]); }
      else       { MM3(accA, xh, xl, B1h[t], B1l[t]); }
    }
    __builtin_amdgcn_s_setprio(0);
    #pragma unroll
    for (int g = 0; g < 16; ++g) accA[g] += accB[g];

    // diag -> norms/invs (per-wave LDS broadcast)
    {
      float s2 = accN[0];
      #pragma unroll
      for (int e = 1; e < 16; ++e) s2 = (gsel == e) ? accN[e] : s2;
      if (own) {
        float n = fmaxf(sqrtf(s2), 1e-8f);
        norms[w][al] = n;
        invs[w][al]  = 1.0f / n;
      }
    }
    asm volatile("s_waitcnt lgkmcnt(0)" ::: "memory");

    unsigned qp[16];
    unsigned flags = 0;
    #pragma unroll
    for (int g = 0; g < 16; ++g) {
      const int r = (g & 3) + 8*(g >> 2) + 4*ah;
      float xr = accA[g] * invs[w][r];
      unsigned q = qt0;
      q = (xr > mid0) ? qt1 : q;  q = (xr > mid1) ? qt2 : q;
      q = (xr > mid2) ? qt3 : q;  q = (xr > mid3) ? qt4 : q;
      q = (xr > mid4) ? qt5 : q;  q = (xr > mid5) ? qt6 : q;
      q = (xr > mid6) ? qt7 : q;
      float dm = fabsf(xr - mid0);
      dm = fminf(dm, fabsf(xr - mid1)); dm = fminf(dm, fabsf(xr - mid2));
      dm = fminf(dm, fabsf(xr - mid3)); dm = fminf(dm, fabsf(xr - mid4));
      dm = fminf(dm, fabsf(xr - mid5)); dm = fminf(dm, fabsf(xr - mid6));
      qp[g] = q;
      flags |= (dm < MARGIN) ? (1u << g) : 0u;
    }
    #pragma unroll
    for (int g = 0; g < 16; ++g) {
      const int rq = (g & 3) + 8*(g >> 2) + 4*ah;
      unsigned off = ((unsigned)(rq*256 + (w*32 + al)*2)) ^ (((unsigned)(rq & 7)) << 4);
      *(unsigned short*)((char*)&Qh[p][0] + off) = (unsigned short)(qp[g] >> 16);
      *(unsigned short*)((char*)&Ql[p][0] + off) = (unsigned short)(qp[g] & 0xFFFFu);
    }
    if (__builtin_amdgcn_ballot_w64(flags != 0)) {   // rare path
      #pragma unroll
      for (int g = 0; g < 16; ++g) {
        unsigned long long b = __ballot((flags >> g) & 1u);
        if (b) {
          const int rq = (g & 3) + 8*(g >> 2) + 4*ah;
          unsigned base = 0;
          if (lane == 0) base = atomicAdd(counter, (unsigned)__popcll(b));
          base = (unsigned)__shfl((int)base, 0);
          if ((flags >> g) & 1u) {
            unsigned pp = base + (unsigned)__popcll(b & ((1ull << lane) - 1ull));
            if (pp < LIST_CAP) list[pp] = (unsigned)(chb + rq);
          }
        }
      }
    }
    LGKM_BAR();                                       // bar2: Q[p] ready

    // ---- Phase C: mm2 (Q[p] x B2 regs), scale + store ----
    f32x16 acc2, acc3;
    #pragma unroll
    for (int g = 0; g < 16; ++g) { acc2[g] = 0.0f; acc3[g] = 0.0f; }
    __builtin_amdgcn_s_setprio(1);
    #pragma unroll
    for (int t = 0; t < 8; ++t) {
      unsigned fb = ((unsigned)(al*256 + t*32 + ah*16)) ^ (((unsigned)(al & 7)) << 4);
      short8 xh = *(const short8*)((const char*)&Qh[p][0] + fb);
      short8 xl = *(const short8*)((const char*)&Ql[p][0] + fb);
      if (t & 1) { MM3(acc3, xh, xl, B2h[t], B2l[t]); }
      else       { MM3(acc2, xh, xl, B2h[t], B2l[t]); }
    }
    __builtin_amdgcn_s_setprio(0);

    #pragma unroll
    for (int g = 0; g < 16; ++g) {
      const int rq = (g & 3) + 8*(g >> 2) + 4*ah;
      float o = fmaf(acc2[g] + acc3[g], norms[w][rq], meanv);
      out[(size_t)(chb + rq)*128 + w*32 + al] = o;
    }
  }
}

// =======================================================================
// K_fix: exact f64 recompute of rows with any element within MARGIN of
// a quantization midpoint. One wave per row; overwrites out. Unchanged.
// =======================================================================
__global__ __launch_bounds__(256)
void kfix(const float* __restrict__ x, const float* __restrict__ mean,
          const float* __restrict__ cent, const double* __restrict__ Rt64,
          float* __restrict__ out,
          const unsigned int* __restrict__ counter,
          const unsigned int* __restrict__ list)
{
  __shared__ double xs[4][128];
  __shared__ double qs[4][128];
  const int tid = threadIdx.x, lane = tid & 63, w = tid >> 6;

  unsigned cnt = *counter;
  if (cnt > LIST_CAP) cnt = LIST_CAP;

  const double cc0 = (double)cent[0], cc1 = (double)cent[1], cc2 = (double)cent[2],
               cc3 = (double)cent[3], cc4 = (double)cent[4], cc5 = (double)cent[5],
               cc6 = (double)cent[6], cc7 = (double)cent[7];
  const double m0 = 0.5*(cc0+cc1), m1 = 0.5*(cc1+cc2), m2 = 0.5*(cc2+cc3),
               m3 = 0.5*(cc3+cc4), m4 = 0.5*(cc4+cc5), m5 = 0.5*(cc5+cc6),
               m6 = 0.5*(cc6+cc7);

  const unsigned gw = blockIdx.x*4 + w, stride = gridDim.x*4;
  for (unsigned e = gw; e < cnt; e += stride) {
    const int row = (int)list[e];
    const float* xr = x + (size_t)row*128;
    const int j0 = 2*lane;

    double a = (double)xr[j0]   - (double)mean[j0];
    double b = (double)xr[j0+1] - (double)mean[j0+1];
    double s = a*a + b*b;
    s += __shfl_xor(s, 1);  s += __shfl_xor(s, 2);  s += __shfl_xor(s, 4);
    s += __shfl_xor(s, 8);  s += __shfl_xor(s, 16); s += __shfl_xor(s, 32);
    double n = sqrt(s);
    if (n < 1e-8) n = 1e-8;
    double inv = 1.0 / n;
    xs[w][j0]   = a * inv;
    xs[w][j0+1] = b * inv;
    asm volatile("s_waitcnt lgkmcnt(0)" ::: "memory");

    double acc0 = 0.0, acc1 = 0.0;
    for (int j = 0; j < 128; ++j) {
      double xj = xs[w][j];
      acc0 = fma(xj, Rt64[j*128 + j0],     acc0);
      acc1 = fma(xj, Rt64[j*128 + j0 + 1], acc1);
    }
    double q0 = cc0;
    q0 = (acc0 > m0) ? cc1 : q0;  q0 = (acc0 > m1) ? cc2 : q0;
    q0 = (acc0 > m2) ? cc3 : q0;  q0 = (acc0 > m3) ? cc4 : q0;
    q0 = (acc0 > m4) ? cc5 : q0;  q0 = (acc0 > m5) ? cc6 : q0;
    q0 = (acc0 > m6) ? cc7 : q0;
    double q1 = cc0;
    q1 = (acc1 > m0) ? cc1 : q1;  q1 = (acc1 > m1) ? cc2 : q1;
    q1 = (acc1 > m2) ? cc3 : q1;  q1 = (acc1 > m3) ? cc4 : q1;
    q1 = (acc1 > m4) ? cc5 : q1;  q1 = (acc1 > m5) ? cc6 : q1;
    q1 = (acc1 > m6) ? cc7 : q1;
    qs[w][j0]   = q0;
    qs[w][j0+1] = q1;
    asm volatile("s_waitcnt lgkmcnt(0)" ::: "memory");

    double o0 = 0.0, o1 = 0.0;
    for (int k = 0; k < 128; ++k) {
      double qk = qs[w][k];
      o0 = fma(qk, Rt64[j0*128 + k],       o0);
      o1 = fma(qk, Rt64[(j0+1)*128 + k],   o1);
    }
    out[(size_t)row*128 + j0]   = (float)fma(o0, n, (double)mean[j0]);
    out[(size_t)row*128 + j0+1] = (float)fma(o1, n, (double)mean[j0+1]);
  }
}

// =======================================================================
extern "C" void kernel_launch(void* const* d_in, const int* in_sizes, int n_in,
                              void* d_out, int out_size, void* d_ws, size_t ws_size,
                              hipStream_t stream)
{
  (void)in_sizes; (void)n_in; (void)out_size; (void)ws_size;
  const float* x    = (const float*)d_in[0];
  const float* skew = (const float*)d_in[1];
  const float* cent = (const float*)d_in[2];
  const float* mean = (const float*)d_in[3];
  float* out = (float*)d_out;

  char* ws = (char*)d_ws;
  double*         Rt64 = (double*)(ws);
  unsigned short* img  = (unsigned short*)(ws + 131072);
  unsigned int*   cntr = (unsigned int*)(ws + 262144);
  unsigned int*   list = (unsigned int*)(ws + 262912);
  double*         M64  = (double*)(ws + 4457216);

  kinv <<<dim3(1),    dim3(1024), 149568, stream>>>(skew, M64, Rt64, img, cntr);
  kmain<<<dim3(1024), dim3(256),  0,      stream>>>(x, mean, cent, img, out, cntr, list);
  kfix <<<dim3(256),  dim3(256),  0,      stream>>>(x, mean, cent, Rt64, out, cntr, list);
}

// Round 14
// 398.287 us; speedup vs baseline: 5.5988x; 5.5988x over previous
//
#include <hip/hip_runtime.h>

#define BATCH 262144
#define MARGIN 1e-5f
#define LIST_CAP (1u<<20)

typedef __attribute__((ext_vector_type(8))) short short8;
typedef __attribute__((ext_vector_type(16))) float f32x16;

// ---------------- workspace layout (bytes) ----------------
// 0       : Rt64 f64[128][128]  Rt64[j*128+k] = R[k][j]      (131072)
// 131072  : img  u16: i1h[16384] i1l[16384] i2h[16384] i2l[16384] (131072)
// 262144  : counter u32
// 262912  : list u32[LIST_CAP]                                (4 MB)
// 4457216 : M64 f64[128][128]   I+A (exact)                   (131072)
// 4588288 : Y64 f64[128][128]   f32-GJ inverse                (131072)
// 4719360 : Yb  f64[128][128]   Newton intermediate           (131072)

__device__ __forceinline__ unsigned f2bf(float f) {
  unsigned u = __float_as_uint(f);
  return (u + 0x7FFFu + ((u >> 16) & 1u)) >> 16;   // RTN-even bf16
}

// =======================================================================
// K_pre32: f32 Gauss-Jordan inversion of M = I + A (round-12 measured
// form; ~100 us spilled but best of 8 attempts -- the single-CU LDS-gemm
// alternative (kinv, round 13) was 2178 us: 16 waves share one LDS pipe).
// Y64 accuracy non-critical: kref's f64 Newton steps square the residual.
// =======================================================================
__global__ __attribute__((amdgpu_waves_per_eu(4, 4))) __launch_bounds__(1024)
void kpre32(const float* __restrict__ skew, double* __restrict__ M64,
            double* __restrict__ Y64, unsigned int* __restrict__ counter)
{
  __shared__ float colk[2][128];
  __shared__ float pivrow[128];
  const int tid = threadIdx.x;
  const int i = tid >> 3;
  const int s = tid & 7;
  if (tid == 0) *counter = 0;

  float M[16];
  #pragma unroll
  for (int e = 0; e < 16; ++e) {
    int j = s + 8*e;
    float v;
    if (i == j)      v = 1.0f;
    else if (i < j)  v =  skew[i*127 - (i*(i-1))/2 + (j - i - 1)];
    else             v = -skew[j*127 - (j*(j-1))/2 + (i - j - 1)];
    M[e] = v;
    M64[i*128 + j] = (double)v;     // exact I+A
  }
  if (s == 0) colk[0][i] = M[0];
  __syncthreads();

  for (int k = 0; k < 128; ++k) {
    const int p = k & 1, np = p ^ 1;
    const int ns = (k + 1) & 7, ne = (k + 1) >> 3;
    if (i == k) {
      float rec = 1.0f / colk[p][k];
      #pragma unroll
      for (int e = 0; e < 16; ++e) {
        int j = s + 8*e;
        float v = (j == k) ? 1.0f : M[e];
        v *= rec;
        M[e] = v;
        pivrow[j] = v;
      }
      if (s == ns && k < 127) colk[np][i] = M[ne];
    }
    __syncthreads();
    if (i != k) {
      float f = colk[p][i];
      #pragma unroll
      for (int e = 0; e < 16; ++e) {
        int j = s + 8*e;
        float v = (j == k) ? 0.0f : M[e];
        M[e] = fmaf(-f, pivrow[j], v);
      }
      if (s == ns && k < 127) colk[np][i] = M[ne];
    }
    __syncthreads();
  }

  #pragma unroll
  for (int e = 0; e < 16; ++e) {
    int j = s + 8*e;
    Y64[i*128 + j] = (double)M[e];
  }
}

// =======================================================================
// K_ref: one f64 Newton-Schulz step Yout = Yin*(2I - M64*Yin), per
// 16-column tile (8 blocks). final_pass: emit R = 2*Y2 - I as Rt64 +
// bf16-split fragment images.
// =======================================================================
__global__ __launch_bounds__(256, 2)
void kref(const double* __restrict__ M64, const double* __restrict__ Yin,
          double* __restrict__ Yout, double* __restrict__ Rt64,
          unsigned short* __restrict__ img, const int final_pass)
{
  __shared__ double Yc[128][17];
  __shared__ double T[128][17];
  const int t = threadIdx.x;
  const int c0 = blockIdx.x * 16;

  #pragma unroll
  for (int u = 0; u < 8; ++u) {
    int idx = u*256 + t;
    int row = idx >> 4, cc = idx & 15;
    Yc[row][cc] = Yin[row*128 + c0 + cc];
  }
  __syncthreads();

  const int m = t >> 1;
  const int h = (t & 1) * 8;

  double a0=0,a1=0,a2=0,a3=0,a4=0,a5=0,a6=0,a7=0;
  for (int j = 0; j < 128; ++j) {
    double mv = M64[m*128 + j];
    a0 = fma(mv, Yc[j][h+0], a0);  a1 = fma(mv, Yc[j][h+1], a1);
    a2 = fma(mv, Yc[j][h+2], a2);  a3 = fma(mv, Yc[j][h+3], a3);
    a4 = fma(mv, Yc[j][h+4], a4);  a5 = fma(mv, Yc[j][h+5], a5);
    a6 = fma(mv, Yc[j][h+6], a6);  a7 = fma(mv, Yc[j][h+7], a7);
  }
  T[m][h+0]=a0; T[m][h+1]=a1; T[m][h+2]=a2; T[m][h+3]=a3;
  T[m][h+4]=a4; T[m][h+5]=a5; T[m][h+6]=a6; T[m][h+7]=a7;
  __syncthreads();

  double b0=0,b1=0,b2=0,b3=0,b4=0,b5=0,b6=0,b7=0;
  for (int j = 0; j < 128; ++j) {
    double yv = Yin[m*128 + j];
    b0 = fma(yv, T[j][h+0], b0);  b1 = fma(yv, T[j][h+1], b1);
    b2 = fma(yv, T[j][h+2], b2);  b3 = fma(yv, T[j][h+3], b3);
    b4 = fma(yv, T[j][h+4], b4);  b5 = fma(yv, T[j][h+5], b5);
    b6 = fma(yv, T[j][h+6], b6);  b7 = fma(yv, T[j][h+7], b7);
  }

  double y2[8] = { 2.0*Yc[m][h+0]-b0, 2.0*Yc[m][h+1]-b1, 2.0*Yc[m][h+2]-b2,
                   2.0*Yc[m][h+3]-b3, 2.0*Yc[m][h+4]-b4, 2.0*Yc[m][h+5]-b5,
                   2.0*Yc[m][h+6]-b6, 2.0*Yc[m][h+7]-b7 };

  if (!final_pass) {
    #pragma unroll
    for (int c = 0; c < 8; ++c) Yout[m*128 + c0 + h + c] = y2[c];
  } else {
    #pragma unroll
    for (int c = 0; c < 8; ++c) {
      const int i = m, j = c0 + h + c;
      double v = 2.0*y2[c] - ((i == j) ? 1.0 : 0.0);    // R[i][j]
      Rt64[j*128 + i] = v;
      float r32 = (float)v;
      unsigned hh = f2bf(r32);
      unsigned ll = f2bf(r32 - __uint_as_float(hh << 16));
      int off1 = (((i>>5)*8 + (j>>4))*64 + ((((j>>3)&1)<<5) | (i&31)))*8 + (j&7);
      img[off1]          = (unsigned short)hh;
      img[16384 + off1]  = (unsigned short)ll;
      int off2 = (((j>>5)*8 + (i>>4))*64 + ((((i>>3)&1)<<5) | (j&31)))*8 + (i&7);
      img[32768 + off2]  = (unsigned short)hh;
      img[49152 + off2]  = (unsigned short)ll;
    }
  }
}

// =======================================================================
// K_main: round-12 structure with SINGLE-buffered X and Q. Correctness:
// X is written in phase A and read in phase B; conflicting next-chunk
// writes are separated by bar2 (LGKM drain) in every wave ordering.
// Q is written in phase B, read in phase C; next-chunk writes are
// separated by bar1. norms/invs are per-wave private. LDS 66.5->33.8 KB
// -> 4 blocks/CU; launch_bounds(256,4) pins the already-achieved
// 128-VGPR allocation -> 16 waves/CU (was 8).
// =======================================================================
#define MM3(ACC, XH, XL, BH, BL)                                        \
  ACC = __builtin_amdgcn_mfma_f32_32x32x16_bf16(XH, BH, ACC, 0, 0, 0);  \
  ACC = __builtin_amdgcn_mfma_f32_32x32x16_bf16(XL, BH, ACC, 0, 0, 0);  \
  ACC = __builtin_amdgcn_mfma_f32_32x32x16_bf16(XH, BL, ACC, 0, 0, 0);

#define LGKM_BAR()                                                      \
  asm volatile("s_waitcnt lgkmcnt(0)" ::: "memory");                    \
  __builtin_amdgcn_s_barrier();                                         \
  __builtin_amdgcn_sched_barrier(0);

__global__ __launch_bounds__(256, 4)
void kmain(const float* __restrict__ x, const float* __restrict__ mean,
           const float* __restrict__ cent, const unsigned short* __restrict__ img,
           float* __restrict__ out,
           unsigned int* __restrict__ counter, unsigned int* __restrict__ list)
{
  __shared__ __align__(16) unsigned short Xh[32*128];   // 8 KB (swizzled)
  __shared__ __align__(16) unsigned short Xl[32*128];
  __shared__ __align__(16) unsigned short Qh[32*128];
  __shared__ __align__(16) unsigned short Ql[32*128];
  __shared__ float norms[4][32];     // per-wave private
  __shared__ float invs[4][32];

  const int tid = threadIdx.x, lane = tid & 63, w = tid >> 6;
  const int al = lane & 31, ah = lane >> 5;

  short8 B1h[8], B1l[8], B2h[8], B2l[8];
  #pragma unroll
  for (int t = 0; t < 8; ++t) {
    size_t o = (size_t)((w*8 + t)*64 + lane)*8;
    B1h[t] = *(const short8*)(img +         o);
    B1l[t] = *(const short8*)(img + 16384 + o);
    B2h[t] = *(const short8*)(img + 32768 + o);
    B2l[t] = *(const short8*)(img + 49152 + o);
  }

  const float c0 = cent[0], c1 = cent[1], c2 = cent[2], c3 = cent[3];
  const float c4 = cent[4], c5 = cent[5], c6 = cent[6], c7 = cent[7];
  const float mid0 = 0.5f*(c0+c1), mid1 = 0.5f*(c1+c2), mid2 = 0.5f*(c2+c3),
              mid3 = 0.5f*(c3+c4), mid4 = 0.5f*(c4+c5), mid5 = 0.5f*(c5+c6),
              mid6 = 0.5f*(c6+c7);
  unsigned qt0, qt1, qt2, qt3, qt4, qt5, qt6, qt7;
  {
    #define PS(C, QT) { unsigned h = f2bf(C); float hf = __uint_as_float(h<<16); \
                        QT = (h<<16) | f2bf((C) - hf); }
    PS(c0,qt0) PS(c1,qt1) PS(c2,qt2) PS(c3,qt3)
    PS(c4,qt4) PS(c5,qt5) PS(c6,qt6) PS(c7,qt7)
    #undef PS
  }

  const float2 mean2 = *(const float2*)(mean + 2*lane);
  const float meanv = mean[w*32 + al];

  const int row0 = blockIdx.x * 256;

  float2 xpf[8];
  #pragma unroll
  for (int rr = 0; rr < 8; ++rr)
    xpf[rr] = *(const float2*)(x + (size_t)(row0 + w*8 + rr)*128 + 2*lane);

  const bool own = (((al >> 2) & 1) == ah);
  const int rrq = al - 4*ah;
  const int gsel = (rrq & 3) + 4*(rrq >> 3);

  for (int ch = 0; ch < 8; ++ch) {
    const int chb = row0 + ch*32;

    // ---- Phase A: issue next-chunk loads; cvt_pk split -> X ----
    float2 xn[8];
    if (ch < 7) {
      #pragma unroll
      for (int rr = 0; rr < 8; ++rr)
        xn[rr] = *(const float2*)(x + (size_t)(chb + 32 + w*8 + rr)*128 + 2*lane);
    }
    #pragma unroll
    for (int rr = 0; rr < 8; ++rr) {
      const int r = w*8 + rr;
      float a = xpf[rr].x - mean2.x;
      float b = xpf[rr].y - mean2.y;
      unsigned ph, pl;
      asm("v_cvt_pk_bf16_f32 %0, %1, %2" : "=v"(ph) : "v"(a), "v"(b));
      float ha = __uint_as_float(ph << 16);
      float hb = __uint_as_float(ph & 0xFFFF0000u);
      float ra = a - ha, rb = b - hb;
      asm("v_cvt_pk_bf16_f32 %0, %1, %2" : "=v"(pl) : "v"(ra), "v"(rb));
      unsigned off = ((unsigned)(r*256 + 4*lane)) ^ (((unsigned)(r & 7)) << 4);
      *(unsigned*)((char*)Xh + off) = ph;
      *(unsigned*)((char*)Xl + off) = pl;
    }
    #pragma unroll
    for (int rr = 0; rr < 8; ++rr) xpf[rr] = xn[rr];
    LGKM_BAR();                                       // bar1: X ready

    // ---- Phase B: norm-MFMA + mm1, quantize, write Q ----
    f32x16 accN, accA, accB;
    #pragma unroll
    for (int g = 0; g < 16; ++g) { accN[g] = 0.0f; accA[g] = 0.0f; accB[g] = 0.0f; }
    __builtin_amdgcn_s_setprio(1);
    #pragma unroll
    for (int t = 0; t < 8; ++t) {
      unsigned fb = ((unsigned)(al*256 + t*32 + ah*16)) ^ (((unsigned)(al & 7)) << 4);
      short8 xh = *(const short8*)((const char*)Xh + fb);
      short8 xl = *(const short8*)((const char*)Xl + fb);
      accN = __builtin_amdgcn_mfma_f32_32x32x16_bf16(xh, xh, accN, 0, 0, 0);
      accN = __builtin_amdgcn_mfma_f32_32x32x16_bf16(xl, xh, accN, 0, 0, 0);
      accN = __builtin_amdgcn_mfma_f32_32x32x16_bf16(xh, xl, accN, 0, 0, 0);
      if (t & 1) { MM3(accB, xh, xl, B1h[t], B1l[t]); }
      else       { MM3(accA, xh, xl, B1h[t], B1l[t]); }
    }
    __builtin_amdgcn_s_setprio(0);
    #pragma unroll
    for (int g = 0; g < 16; ++g) accA[g] += accB[g];

    // diag -> norms/invs (per-wave LDS broadcast)
    {
      float s2 = accN[0];
      #pragma unroll
      for (int e = 1; e < 16; ++e) s2 = (gsel == e) ? accN[e] : s2;
      if (own) {
        float n = fmaxf(sqrtf(s2), 1e-8f);
        norms[w][al] = n;
        invs[w][al]  = 1.0f / n;
      }
    }
    asm volatile("s_waitcnt lgkmcnt(0)" ::: "memory");

    unsigned qp[16];
    unsigned flags = 0;
    #pragma unroll
    for (int g = 0; g < 16; ++g) {
      const int r = (g & 3) + 8*(g >> 2) + 4*ah;
      float xr = accA[g] * invs[w][r];
      unsigned q = qt0;
      q = (xr > mid0) ? qt1 : q;  q = (xr > mid1) ? qt2 : q;
      q = (xr > mid2) ? qt3 : q;  q = (xr > mid3) ? qt4 : q;
      q = (xr > mid4) ? qt5 : q;  q = (xr > mid5) ? qt6 : q;
      q = (xr > mid6) ? qt7 : q;
      float dm = fabsf(xr - mid0);
      dm = fminf(dm, fabsf(xr - mid1)); dm = fminf(dm, fabsf(xr - mid2));
      dm = fminf(dm, fabsf(xr - mid3)); dm = fminf(dm, fabsf(xr - mid4));
      dm = fminf(dm, fabsf(xr - mid5)); dm = fminf(dm, fabsf(xr - mid6));
      qp[g] = q;
      flags |= (dm < MARGIN) ? (1u << g) : 0u;
    }
    #pragma unroll
    for (int g = 0; g < 16; ++g) {
      const int rq = (g & 3) + 8*(g >> 2) + 4*ah;
      unsigned off = ((unsigned)(rq*256 + (w*32 + al)*2)) ^ (((unsigned)(rq & 7)) << 4);
      *(unsigned short*)((char*)Qh + off) = (unsigned short)(qp[g] >> 16);
      *(unsigned short*)((char*)Ql + off) = (unsigned short)(qp[g] & 0xFFFFu);
    }
    if (__builtin_amdgcn_ballot_w64(flags != 0)) {   // rare path
      #pragma unroll
      for (int g = 0; g < 16; ++g) {
        unsigned long long b = __ballot((flags >> g) & 1u);
        if (b) {
          const int rq = (g & 3) + 8*(g >> 2) + 4*ah;
          unsigned base = 0;
          if (lane == 0) base = atomicAdd(counter, (unsigned)__popcll(b));
          base = (unsigned)__shfl((int)base, 0);
          if ((flags >> g) & 1u) {
            unsigned pp = base + (unsigned)__popcll(b & ((1ull << lane) - 1ull));
            if (pp < LIST_CAP) list[pp] = (unsigned)(chb + rq);
          }
        }
      }
    }
    LGKM_BAR();                                       // bar2: Q ready

    // ---- Phase C: mm2 (Q x B2 regs), scale + store ----
    f32x16 acc2, acc3;
    #pragma unroll
    for (int g = 0; g < 16; ++g) { acc2[g] = 0.0f; acc3[g] = 0.0f; }
    __builtin_amdgcn_s_setprio(1);
    #pragma unroll
    for (int t = 0; t < 8; ++t) {
      unsigned fb = ((unsigned)(al*256 + t*32 + ah*16)) ^ (((unsigned)(al & 7)) << 4);
      short8 xh = *(const short8*)((const char*)Qh + fb);
      short8 xl = *(const short8*)((const char*)Ql + fb);
      if (t & 1) { MM3(acc3, xh, xl, B2h[t], B2l[t]); }
      else       { MM3(acc2, xh, xl, B2h[t], B2l[t]); }
    }
    __builtin_amdgcn_s_setprio(0);

    #pragma unroll
    for (int g = 0; g < 16; ++g) {
      const int rq = (g & 3) + 8*(g >> 2) + 4*ah;
      float o = fmaf(acc2[g] + acc3[g], norms[w][rq], meanv);
      out[(size_t)(chb + rq)*128 + w*32 + al] = o;
    }
  }
}

// =======================================================================
// K_fix: exact f64 recompute of rows with any element within MARGIN of
// a quantization midpoint. One wave per row; overwrites out. Unchanged.
// =======================================================================
__global__ __launch_bounds__(256)
void kfix(const float* __restrict__ x, const float* __restrict__ mean,
          const float* __restrict__ cent, const double* __restrict__ Rt64,
          float* __restrict__ out,
          const unsigned int* __restrict__ counter,
          const unsigned int* __restrict__ list)
{
  __shared__ double xs[4][128];
  __shared__ double qs[4][128];
  const int tid = threadIdx.x, lane = tid & 63, w = tid >> 6;

  unsigned cnt = *counter;
  if (cnt > LIST_CAP) cnt = LIST_CAP;

  const double cc0 = (double)cent[0], cc1 = (double)cent[1], cc2 = (double)cent[2],
               cc3 = (double)cent[3], cc4 = (double)cent[4], cc5 = (double)cent[5],
               cc6 = (double)cent[6], cc7 = (double)cent[7];
  const double m0 = 0.5*(cc0+cc1), m1 = 0.5*(cc1+cc2), m2 = 0.5*(cc2+cc3),
               m3 = 0.5*(cc3+cc4), m4 = 0.5*(cc4+cc5), m5 = 0.5*(cc5+cc6),
               m6 = 0.5*(cc6+cc7);

  const unsigned gw = blockIdx.x*4 + w, stride = gridDim.x*4;
  for (unsigned e = gw; e < cnt; e += stride) {
    const int row = (int)list[e];
    const float* xr = x + (size_t)row*128;
    const int j0 = 2*lane;

    double a = (double)xr[j0]   - (double)mean[j0];
    double b = (double)xr[j0+1] - (double)mean[j0+1];
    double s = a*a + b*b;
    s += __shfl_xor(s, 1);  s += __shfl_xor(s, 2);  s += __shfl_xor(s, 4);
    s += __shfl_xor(s, 8);  s += __shfl_xor(s, 16); s += __shfl_xor(s, 32);
    double n = sqrt(s);
    if (n < 1e-8) n = 1e-8;
    double inv = 1.0 / n;
    xs[w][j0]   = a * inv;
    xs[w][j0+1] = b * inv;
    asm volatile("s_waitcnt lgkmcnt(0)" ::: "memory");

    double acc0 = 0.0, acc1 = 0.0;
    for (int j = 0; j < 128; ++j) {
      double xj = xs[w][j];
      acc0 = fma(xj, Rt64[j*128 + j0],     acc0);
      acc1 = fma(xj, Rt64[j*128 + j0 + 1], acc1);
    }
    double q0 = cc0;
    q0 = (acc0 > m0) ? cc1 : q0;  q0 = (acc0 > m1) ? cc2 : q0;
    q0 = (acc0 > m2) ? cc3 : q0;  q0 = (acc0 > m3) ? cc4 : q0;
    q0 = (acc0 > m4) ? cc5 : q0;  q0 = (acc0 > m5) ? cc6 : q0;
    q0 = (acc0 > m6) ? cc7 : q0;
    double q1 = cc0;
    q1 = (acc1 > m0) ? cc1 : q1;  q1 = (acc1 > m1) ? cc2 : q1;
    q1 = (acc1 > m2) ? cc3 : q1;  q1 = (acc1 > m3) ? cc4 : q1;
    q1 = (acc1 > m4) ? cc5 : q1;  q1 = (acc1 > m5) ? cc6 : q1;
    q1 = (acc1 > m6) ? cc7 : q1;
    qs[w][j0]   = q0;
    qs[w][j0+1] = q1;
    asm volatile("s_waitcnt lgkmcnt(0)" ::: "memory");

    double o0 = 0.0, o1 = 0.0;
    for (int k = 0; k < 128; ++k) {
      double qk = qs[w][k];
      o0 = fma(qk, Rt64[j0*128 + k],       o0);
      o1 = fma(qk, Rt64[(j0+1)*128 + k],   o1);
    }
    out[(size_t)row*128 + j0]   = (float)fma(o0, n, (double)mean[j0]);
    out[(size_t)row*128 + j0+1] = (float)fma(o1, n, (double)mean[j0+1]);
  }
}

// =======================================================================
extern "C" void kernel_launch(void* const* d_in, const int* in_sizes, int n_in,
                              void* d_out, int out_size, void* d_ws, size_t ws_size,
                              hipStream_t stream)
{
  (void)in_sizes; (void)n_in; (void)out_size; (void)ws_size;
  const float* x    = (const float*)d_in[0];
  const float* skew = (const float*)d_in[1];
  const float* cent = (const float*)d_in[2];
  const float* mean = (const float*)d_in[3];
  float* out = (float*)d_out;

  char* ws = (char*)d_ws;
  double*         Rt64 = (double*)(ws);
  unsigned short* img  = (unsigned short*)(ws + 131072);
  unsigned int*   cntr = (unsigned int*)(ws + 262144);
  unsigned int*   list = (unsigned int*)(ws + 262912);
  double*         M64  = (double*)(ws + 4457216);
  double*         Y64  = (double*)(ws + 4588288);
  double*         Yb   = (double*)(ws + 4719360);

  kpre32<<<dim3(1),    dim3(1024), 0, stream>>>(skew, M64, Y64, cntr);
  kref  <<<dim3(8),    dim3(256),  0, stream>>>(M64, Y64, Yb, Rt64, img, 0);
  kref  <<<dim3(8),    dim3(256),  0, stream>>>(M64, Yb, Y64, Rt64, img, 1);
  kmain <<<dim3(1024), dim3(256),  0, stream>>>(x, mean, cent, img, out, cntr, list);
  kfix  <<<dim3(256),  dim3(256),  0, stream>>>(x, mean, cent, Rt64, out, cntr, list);
}

// Round 15
// 248.380 us; speedup vs baseline: 8.9779x; 1.6035x over previous
//
#include <hip/hip_runtime.h>

#define BATCH 262144
#define MARGIN 1e-5f
#define LIST_CAP (1u<<20)

typedef __attribute__((ext_vector_type(8))) short short8;
typedef __attribute__((ext_vector_type(16))) float f32x16;

// ---------------- workspace layout (bytes) ----------------
// 0       : Rt64 f64[128][128]  Rt64[j*128+k] = R[k][j]      (131072)
// 131072  : img  u16: i1h[16384] i1l[16384] i2h[16384] i2l[16384] (131072)
// 262144  : counter u32
// 262912  : list u32[LIST_CAP]                                (4 MB)
// 4457216 : M64 f64[128][128]   I+A (exact)                   (131072)
// 4588288 : Y64 f64[128][128]   f32-GJ inverse                (131072)
// 4719360 : Yb  f64[128][128]   Newton intermediate           (131072)
// 4850432 : normg f32[BATCH]                                  (1048576)
// 5899008 : invg  f32[BATCH]                                  (1048576)

__device__ __forceinline__ unsigned f2bf(float f) {
  unsigned u = __float_as_uint(f);
  return (u + 0x7FFFu + ((u >> 16) & 1u)) >> 16;   // RTN-even bf16
}

// =======================================================================
// K_pre: block 0 = round-12 f32 GJ (spilled-but-fastest of 9 attempts;
// ~100 us on one CU). Blocks 1..256 fill that bubble computing all row
// norms (134 MB HBM ~30 us, hidden; also pre-warms L3 with x for kmain).
// Y64 accuracy non-critical: kref's f64 Newton steps square the residual.
// =======================================================================
__global__ __attribute__((amdgpu_waves_per_eu(4, 4))) __launch_bounds__(1024)
void kpre(const float* __restrict__ skew, const float* __restrict__ x,
          const float* __restrict__ mean, double* __restrict__ M64,
          double* __restrict__ Y64, float* __restrict__ normg,
          float* __restrict__ invg, unsigned int* __restrict__ counter)
{
  const int tid = threadIdx.x;

  if (blockIdx.x != 0) {
    // ---- norm blocks: 16 waves x 64 rows each ----
    const int b  = blockIdx.x - 1;
    const int wv = tid >> 6, ln = tid & 63;
    const int rowbase = b*1024 + wv*64;
    const float2 mv = *(const float2*)(mean + 2*ln);
    for (int i = 0; i < 64; ++i) {
      const int row = rowbase + i;
      float2 xv = *(const float2*)(x + (size_t)row*128 + 2*ln);
      float a = xv.x - mv.x, c = xv.y - mv.y;
      float sq = fmaf(a, a, c*c);
      sq += __shfl_xor(sq, 1);  sq += __shfl_xor(sq, 2);  sq += __shfl_xor(sq, 4);
      sq += __shfl_xor(sq, 8);  sq += __shfl_xor(sq, 16); sq += __shfl_xor(sq, 32);
      if (ln == 0) {
        float n = fmaxf(sqrtf(sq), 1e-8f);
        normg[row] = n;
        invg[row]  = 1.0f / n;
      }
    }
    return;
  }

  // ---- block 0: f32 Gauss-Jordan of M = I + A (no pivoting) ----
  __shared__ float colk[2][128];
  __shared__ float pivrow[128];
  const int i = tid >> 3;
  const int s = tid & 7;
  if (tid == 0) *counter = 0;

  float M[16];
  #pragma unroll
  for (int e = 0; e < 16; ++e) {
    int j = s + 8*e;
    float v;
    if (i == j)      v = 1.0f;
    else if (i < j)  v =  skew[i*127 - (i*(i-1))/2 + (j - i - 1)];
    else             v = -skew[j*127 - (j*(j-1))/2 + (i - j - 1)];
    M[e] = v;
    M64[i*128 + j] = (double)v;     // exact I+A
  }
  if (s == 0) colk[0][i] = M[0];
  __syncthreads();

  for (int k = 0; k < 128; ++k) {
    const int p = k & 1, np = p ^ 1;
    const int ns = (k + 1) & 7, ne = (k + 1) >> 3;
    if (i == k) {
      float rec = 1.0f / colk[p][k];
      #pragma unroll
      for (int e = 0; e < 16; ++e) {
        int j = s + 8*e;
        float v = (j == k) ? 1.0f : M[e];
        v *= rec;
        M[e] = v;
        pivrow[j] = v;
      }
      if (s == ns && k < 127) colk[np][i] = M[ne];
    }
    __syncthreads();
    if (i != k) {
      float f = colk[p][i];
      #pragma unroll
      for (int e = 0; e < 16; ++e) {
        int j = s + 8*e;
        float v = (j == k) ? 0.0f : M[e];
        M[e] = fmaf(-f, pivrow[j], v);
      }
      if (s == ns && k < 127) colk[np][i] = M[ne];
    }
    __syncthreads();
  }

  #pragma unroll
  for (int e = 0; e < 16; ++e) {
    int j = s + 8*e;
    Y64[i*128 + j] = (double)M[e];
  }
}

// =======================================================================
// K_ref: one f64 Newton-Schulz step Yout = Yin*(2I - M64*Yin), per
// 16-column tile (8 blocks). final_pass: emit R = 2*Y2 - I as Rt64 +
// bf16-split fragment images.
// =======================================================================
__global__ __launch_bounds__(256, 2)
void kref(const double* __restrict__ M64, const double* __restrict__ Yin,
          double* __restrict__ Yout, double* __restrict__ Rt64,
          unsigned short* __restrict__ img, const int final_pass)
{
  __shared__ double Yc[128][17];
  __shared__ double T[128][17];
  const int t = threadIdx.x;
  const int c0 = blockIdx.x * 16;

  #pragma unroll
  for (int u = 0; u < 8; ++u) {
    int idx = u*256 + t;
    int row = idx >> 4, cc = idx & 15;
    Yc[row][cc] = Yin[row*128 + c0 + cc];
  }
  __syncthreads();

  const int m = t >> 1;
  const int h = (t & 1) * 8;

  double a0=0,a1=0,a2=0,a3=0,a4=0,a5=0,a6=0,a7=0;
  for (int j = 0; j < 128; ++j) {
    double mv = M64[m*128 + j];
    a0 = fma(mv, Yc[j][h+0], a0);  a1 = fma(mv, Yc[j][h+1], a1);
    a2 = fma(mv, Yc[j][h+2], a2);  a3 = fma(mv, Yc[j][h+3], a3);
    a4 = fma(mv, Yc[j][h+4], a4);  a5 = fma(mv, Yc[j][h+5], a5);
    a6 = fma(mv, Yc[j][h+6], a6);  a7 = fma(mv, Yc[j][h+7], a7);
  }
  T[m][h+0]=a0; T[m][h+1]=a1; T[m][h+2]=a2; T[m][h+3]=a3;
  T[m][h+4]=a4; T[m][h+5]=a5; T[m][h+6]=a6; T[m][h+7]=a7;
  __syncthreads();

  double b0=0,b1=0,b2=0,b3=0,b4=0,b5=0,b6=0,b7=0;
  for (int j = 0; j < 128; ++j) {
    double yv = Yin[m*128 + j];
    b0 = fma(yv, T[j][h+0], b0);  b1 = fma(yv, T[j][h+1], b1);
    b2 = fma(yv, T[j][h+2], b2);  b3 = fma(yv, T[j][h+3], b3);
    b4 = fma(yv, T[j][h+4], b4);  b5 = fma(yv, T[j][h+5], b5);
    b6 = fma(yv, T[j][h+6], b6);  b7 = fma(yv, T[j][h+7], b7);
  }

  double y2[8] = { 2.0*Yc[m][h+0]-b0, 2.0*Yc[m][h+1]-b1, 2.0*Yc[m][h+2]-b2,
                   2.0*Yc[m][h+3]-b3, 2.0*Yc[m][h+4]-b4, 2.0*Yc[m][h+5]-b5,
                   2.0*Yc[m][h+6]-b6, 2.0*Yc[m][h+7]-b7 };

  if (!final_pass) {
    #pragma unroll
    for (int c = 0; c < 8; ++c) Yout[m*128 + c0 + h + c] = y2[c];
  } else {
    #pragma unroll
    for (int c = 0; c < 8; ++c) {
      const int i = m, j = c0 + h + c;
      double v = 2.0*y2[c] - ((i == j) ? 1.0 : 0.0);    // R[i][j]
      Rt64[j*128 + i] = v;
      float r32 = (float)v;
      unsigned hh = f2bf(r32);
      unsigned ll = f2bf(r32 - __uint_as_float(hh << 16));
      int off1 = (((i>>5)*8 + (j>>4))*64 + ((((j>>3)&1)<<5) | (i&31)))*8 + (j&7);
      img[off1]          = (unsigned short)hh;
      img[16384 + off1]  = (unsigned short)ll;
      int off2 = (((j>>5)*8 + (i>>4))*64 + ((((i>>3)&1)<<5) | (j&31)))*8 + (i&7);
      img[32768 + off2]  = (unsigned short)hh;
      img[49152 + off2]  = (unsigned short)ll;
    }
  }
}

// =======================================================================
// K_main: round-12 structure (B1+B2 in regs, X/Q double-buffered, lgkm
// barriers, launch_bounds(256,2) -- unified VGPR+AGPR need ~208 regs, so
// 2 waves/SIMD is structural; (256,4)/(waves3) both spilled). CHANGE:
// norm-MFMA chain removed (24 of 72 MFMAs/chunk) -- norms precomputed by
// kpre's norm blocks, loaded into per-wave LDS broadcast (race-free).
// =======================================================================
#define MM3(ACC, XH, XL, BH, BL)                                        \
  ACC = __builtin_amdgcn_mfma_f32_32x32x16_bf16(XH, BH, ACC, 0, 0, 0);  \
  ACC = __builtin_amdgcn_mfma_f32_32x32x16_bf16(XL, BH, ACC, 0, 0, 0);  \
  ACC = __builtin_amdgcn_mfma_f32_32x32x16_bf16(XH, BL, ACC, 0, 0, 0);

#define LGKM_BAR()                                                      \
  asm volatile("s_waitcnt lgkmcnt(0)" ::: "memory");                    \
  __builtin_amdgcn_s_barrier();                                         \
  __builtin_amdgcn_sched_barrier(0);

__global__ __launch_bounds__(256, 2)
void kmain(const float* __restrict__ x, const float* __restrict__ mean,
           const float* __restrict__ cent, const unsigned short* __restrict__ img,
           const float* __restrict__ normg, const float* __restrict__ invg,
           float* __restrict__ out,
           unsigned int* __restrict__ counter, unsigned int* __restrict__ list)
{
  __shared__ __align__(16) unsigned short Xh[2][32*128];
  __shared__ __align__(16) unsigned short Xl[2][32*128];
  __shared__ __align__(16) unsigned short Qh[2][32*128];
  __shared__ __align__(16) unsigned short Ql[2][32*128];
  __shared__ float norms[4][32];     // per-wave private
  __shared__ float invs[4][32];

  const int tid = threadIdx.x, lane = tid & 63, w = tid >> 6;
  const int al = lane & 31, ah = lane >> 5;

  short8 B1h[8], B1l[8], B2h[8], B2l[8];
  #pragma unroll
  for (int t = 0; t < 8; ++t) {
    size_t o = (size_t)((w*8 + t)*64 + lane)*8;
    B1h[t] = *(const short8*)(img +         o);
    B1l[t] = *(const short8*)(img + 16384 + o);
    B2h[t] = *(const short8*)(img + 32768 + o);
    B2l[t] = *(const short8*)(img + 49152 + o);
  }

  const float c0 = cent[0], c1 = cent[1], c2 = cent[2], c3 = cent[3];
  const float c4 = cent[4], c5 = cent[5], c6 = cent[6], c7 = cent[7];
  const float mid0 = 0.5f*(c0+c1), mid1 = 0.5f*(c1+c2), mid2 = 0.5f*(c2+c3),
              mid3 = 0.5f*(c3+c4), mid4 = 0.5f*(c4+c5), mid5 = 0.5f*(c5+c6),
              mid6 = 0.5f*(c6+c7);
  unsigned qt0, qt1, qt2, qt3, qt4, qt5, qt6, qt7;
  {
    #define PS(C, QT) { unsigned h = f2bf(C); float hf = __uint_as_float(h<<16); \
                        QT = (h<<16) | f2bf((C) - hf); }
    PS(c0,qt0) PS(c1,qt1) PS(c2,qt2) PS(c3,qt3)
    PS(c4,qt4) PS(c5,qt5) PS(c6,qt6) PS(c7,qt7)
    #undef PS
  }

  const float2 mean2 = *(const float2*)(mean + 2*lane);
  const float meanv = mean[w*32 + al];

  const int row0 = blockIdx.x * 256;

  float2 xpf[8];
  #pragma unroll
  for (int rr = 0; rr < 8; ++rr)
    xpf[rr] = *(const float2*)(x + (size_t)(row0 + w*8 + rr)*128 + 2*lane);

  for (int ch = 0; ch < 8; ++ch) {
    const int chb = row0 + ch*32;
    const int p = ch & 1;

    // ---- Phase A: next-chunk loads; norm load; cvt_pk split -> X[p] ----
    if (ah == 0) {                         // lanes 0..31: per-wave norm bcast
      norms[w][al] = normg[chb + al];
      invs[w][al]  = invg[chb + al];
    }
    float2 xn[8];
    if (ch < 7) {
      #pragma unroll
      for (int rr = 0; rr < 8; ++rr)
        xn[rr] = *(const float2*)(x + (size_t)(chb + 32 + w*8 + rr)*128 + 2*lane);
    }
    #pragma unroll
    for (int rr = 0; rr < 8; ++rr) {
      const int r = w*8 + rr;
      float a = xpf[rr].x - mean2.x;
      float b = xpf[rr].y - mean2.y;
      unsigned ph, pl;
      asm("v_cvt_pk_bf16_f32 %0, %1, %2" : "=v"(ph) : "v"(a), "v"(b));
      float ha = __uint_as_float(ph << 16);
      float hb = __uint_as_float(ph & 0xFFFF0000u);
      float ra = a - ha, rb = b - hb;
      asm("v_cvt_pk_bf16_f32 %0, %1, %2" : "=v"(pl) : "v"(ra), "v"(rb));
      unsigned off = ((unsigned)(r*256 + 4*lane)) ^ (((unsigned)(r & 7)) << 4);
      *(unsigned*)((char*)&Xh[p][0] + off) = ph;
      *(unsigned*)((char*)&Xl[p][0] + off) = pl;
    }
    #pragma unroll
    for (int rr = 0; rr < 8; ++rr) xpf[rr] = xn[rr];
    LGKM_BAR();                                       // bar1: X[p]+norms ready

    // ---- Phase B: mm1, quantize, write Q[p] ----
    f32x16 accA, accB;
    #pragma unroll
    for (int g = 0; g < 16; ++g) { accA[g] = 0.0f; accB[g] = 0.0f; }
    __builtin_amdgcn_s_setprio(1);
    #pragma unroll
    for (int t = 0; t < 8; ++t) {
      unsigned fb = ((unsigned)(al*256 + t*32 + ah*16)) ^ (((unsigned)(al & 7)) << 4);
      short8 xh = *(const short8*)((const char*)&Xh[p][0] + fb);
      short8 xl = *(const short8*)((const char*)&Xl[p][0] + fb);
      if (t & 1) { MM3(accB, xh, xl, B1h[t], B1l[t]); }
      else       { MM3(accA, xh, xl, B1h[t], B1l[t]); }
    }
    __builtin_amdgcn_s_setprio(0);
    #pragma unroll
    for (int g = 0; g < 16; ++g) accA[g] += accB[g];

    unsigned qp[16];
    unsigned flags = 0;
    #pragma unroll
    for (int g = 0; g < 16; ++g) {
      const int r = (g & 3) + 8*(g >> 2) + 4*ah;
      float xr = accA[g] * invs[w][r];
      unsigned q = qt0;
      q = (xr > mid0) ? qt1 : q;  q = (xr > mid1) ? qt2 : q;
      q = (xr > mid2) ? qt3 : q;  q = (xr > mid3) ? qt4 : q;
      q = (xr > mid4) ? qt5 : q;  q = (xr > mid5) ? qt6 : q;
      q = (xr > mid6) ? qt7 : q;
      float dm = fabsf(xr - mid0);
      dm = fminf(dm, fabsf(xr - mid1)); dm = fminf(dm, fabsf(xr - mid2));
      dm = fminf(dm, fabsf(xr - mid3)); dm = fminf(dm, fabsf(xr - mid4));
      dm = fminf(dm, fabsf(xr - mid5)); dm = fminf(dm, fabsf(xr - mid6));
      qp[g] = q;
      flags |= (dm < MARGIN) ? (1u << g) : 0u;
    }
    #pragma unroll
    for (int g = 0; g < 16; ++g) {
      const int rq = (g & 3) + 8*(g >> 2) + 4*ah;
      unsigned off = ((unsigned)(rq*256 + (w*32 + al)*2)) ^ (((unsigned)(rq & 7)) << 4);
      *(unsigned short*)((char*)&Qh[p][0] + off) = (unsigned short)(qp[g] >> 16);
      *(unsigned short*)((char*)&Ql[p][0] + off) = (unsigned short)(qp[g] & 0xFFFFu);
    }
    if (__builtin_amdgcn_ballot_w64(flags != 0)) {   // rare path
      #pragma unroll
      for (int g = 0; g < 16; ++g) {
        unsigned long long b = __ballot((flags >> g) & 1u);
        if (b) {
          const int rq = (g & 3) + 8*(g >> 2) + 4*ah;
          unsigned base = 0;
          if (lane == 0) base = atomicAdd(counter, (unsigned)__popcll(b));
          base = (unsigned)__shfl((int)base, 0);
          if ((flags >> g) & 1u) {
            unsigned pp = base + (unsigned)__popcll(b & ((1ull << lane) - 1ull));
            if (pp < LIST_CAP) list[pp] = (unsigned)(chb + rq);
          }
        }
      }
    }
    LGKM_BAR();                                       // bar2: Q[p] ready

    // ---- Phase C: mm2 (Q[p] x B2 regs), scale + store ----
    f32x16 acc2, acc3;
    #pragma unroll
    for (int g = 0; g < 16; ++g) { acc2[g] = 0.0f; acc3[g] = 0.0f; }
    __builtin_amdgcn_s_setprio(1);
    #pragma unroll
    for (int t = 0; t < 8; ++t) {
      unsigned fb = ((unsigned)(al*256 + t*32 + ah*16)) ^ (((unsigned)(al & 7)) << 4);
      short8 xh = *(const short8*)((const char*)&Qh[p][0] + fb);
      short8 xl = *(const short8*)((const char*)&Ql[p][0] + fb);
      if (t & 1) { MM3(acc3, xh, xl, B2h[t], B2l[t]); }
      else       { MM3(acc2, xh, xl, B2h[t], B2l[t]); }
    }
    __builtin_amdgcn_s_setprio(0);

    #pragma unroll
    for (int g = 0; g < 16; ++g) {
      const int rq = (g & 3) + 8*(g >> 2) + 4*ah;
      float o = fmaf(acc2[g] + acc3[g], norms[w][rq], meanv);
      out[(size_t)(chb + rq)*128 + w*32 + al] = o;
    }
  }
}

// =======================================================================
// K_fix: exact f64 recompute of rows with any element within MARGIN of
// a quantization midpoint. One wave per row; overwrites out. Unchanged.
// =======================================================================
__global__ __launch_bounds__(256)
void kfix(const float* __restrict__ x, const float* __restrict__ mean,
          const float* __restrict__ cent, const double* __restrict__ Rt64,
          float* __restrict__ out,
          const unsigned int* __restrict__ counter,
          const unsigned int* __restrict__ list)
{
  __shared__ double xs[4][128];
  __shared__ double qs[4][128];
  const int tid = threadIdx.x, lane = tid & 63, w = tid >> 6;

  unsigned cnt = *counter;
  if (cnt > LIST_CAP) cnt = LIST_CAP;

  const double cc0 = (double)cent[0], cc1 = (double)cent[1], cc2 = (double)cent[2],
               cc3 = (double)cent[3], cc4 = (double)cent[4], cc5 = (double)cent[5],
               cc6 = (double)cent[6], cc7 = (double)cent[7];
  const double m0 = 0.5*(cc0+cc1), m1 = 0.5*(cc1+cc2), m2 = 0.5*(cc2+cc3),
               m3 = 0.5*(cc3+cc4), m4 = 0.5*(cc4+cc5), m5 = 0.5*(cc5+cc6),
               m6 = 0.5*(cc6+cc7);

  const unsigned gw = blockIdx.x*4 + w, stride = gridDim.x*4;
  for (unsigned e = gw; e < cnt; e += stride) {
    const int row = (int)list[e];
    const float* xr = x + (size_t)row*128;
    const int j0 = 2*lane;

    double a = (double)xr[j0]   - (double)mean[j0];
    double b = (double)xr[j0+1] - (double)mean[j0+1];
    double s = a*a + b*b;
    s += __shfl_xor(s, 1);  s += __shfl_xor(s, 2);  s += __shfl_xor(s, 4);
    s += __shfl_xor(s, 8);  s += __shfl_xor(s, 16); s += __shfl_xor(s, 32);
    double n = sqrt(s);
    if (n < 1e-8) n = 1e-8;
    double inv = 1.0 / n;
    xs[w][j0]   = a * inv;
    xs[w][j0+1] = b * inv;
    asm volatile("s_waitcnt lgkmcnt(0)" ::: "memory");

    double acc0 = 0.0, acc1 = 0.0;
    for (int j = 0; j < 128; ++j) {
      double xj = xs[w][j];
      acc0 = fma(xj, Rt64[j*128 + j0],     acc0);
      acc1 = fma(xj, Rt64[j*128 + j0 + 1], acc1);
    }
    double q0 = cc0;
    q0 = (acc0 > m0) ? cc1 : q0;  q0 = (acc0 > m1) ? cc2 : q0;
    q0 = (acc0 > m2) ? cc3 : q0;  q0 = (acc0 > m3) ? cc4 : q0;
    q0 = (acc0 > m4) ? cc5 : q0;  q0 = (acc0 > m5) ? cc6 : q0;
    q0 = (acc0 > m6) ? cc7 : q0;
    double q1 = cc0;
    q1 = (acc1 > m0) ? cc1 : q1;  q1 = (acc1 > m1) ? cc2 : q1;
    q1 = (acc1 > m2) ? cc3 : q1;  q1 = (acc1 > m3) ? cc4 : q1;
    q1 = (acc1 > m4) ? cc5 : q1;  q1 = (acc1 > m5) ? cc6 : q1;
    q1 = (acc1 > m6) ? cc7 : q1;
    qs[w][j0]   = q0;
    qs[w][j0+1] = q1;
    asm volatile("s_waitcnt lgkmcnt(0)" ::: "memory");

    double o0 = 0.0, o1 = 0.0;
    for (int k = 0; k < 128; ++k) {
      double qk = qs[w][k];
      o0 = fma(qk, Rt64[j0*128 + k],       o0);
      o1 = fma(qk, Rt64[(j0+1)*128 + k],   o1);
    }
    out[(size_t)row*128 + j0]   = (float)fma(o0, n, (double)mean[j0]);
    out[(size_t)row*128 + j0+1] = (float)fma(o1, n, (double)mean[j0+1]);
  }
}

// =======================================================================
extern "C" void kernel_launch(void* const* d_in, const int* in_sizes, int n_in,
                              void* d_out, int out_size, void* d_ws, size_t ws_size,
                              hipStream_t stream)
{
  (void)in_sizes; (void)n_in; (void)out_size; (void)ws_size;
  const float* x    = (const float*)d_in[0];
  const float* skew = (const float*)d_in[1];
  const float* cent = (const float*)d_in[2];
  const float* mean = (const float*)d_in[3];
  float* out = (float*)d_out;

  char* ws = (char*)d_ws;
  double*         Rt64  = (double*)(ws);
  unsigned short* img   = (unsigned short*)(ws + 131072);
  unsigned int*   cntr  = (unsigned int*)(ws + 262144);
  unsigned int*   list  = (unsigned int*)(ws + 262912);
  double*         M64   = (double*)(ws + 4457216);
  double*         Y64   = (double*)(ws + 4588288);
  double*         Yb    = (double*)(ws + 4719360);
  float*          normg = (float*)(ws + 4850432);
  float*          invg  = (float*)(ws + 5899008);

  kpre <<<dim3(257),  dim3(1024), 0, stream>>>(skew, x, mean, M64, Y64,
                                               normg, invg, cntr);
  kref <<<dim3(8),    dim3(256),  0, stream>>>(M64, Y64, Yb, Rt64, img, 0);
  kref <<<dim3(8),    dim3(256),  0, stream>>>(M64, Yb, Y64, Rt64, img, 1);
  kmain<<<dim3(1024), dim3(256),  0, stream>>>(x, mean, cent, img, normg, invg,
                                               out, cntr, list);
  kfix <<<dim3(256),  dim3(256),  0, stream>>>(x, mean, cent, Rt64, out, cntr, list);
}